// Round 4
// baseline (902.996 us; speedup 1.0000x reference)
//
#include <hip/hip_runtime.h>

// ---------------------------------------------------------------------------
// GraphAggregator v5: persistent blocks (512 = 2/CU, fully resident), each
// sweeping a contiguous range of ~12 row-tiles as ONE software pipeline:
//  - cross-tile K-loop: at ks=6/7 loads target the NEXT tile's ks0/ks1, so
//    the softmax/pooling epilogue overlaps next-tile x fetches, and the
//    block prologue happens once per block (12x amortization).
//  - reg-staged x (empirically best) with conflict-free slab layout:
//    staging writes are lane-linear 8B (2-way alias = free), A-frag reads
//    are lane-linear ds_read_b128. bf16 in LDS (4 KB/slab), cvt at staging
//    via v_cvt_pk_bf16_f32 (RNE).
//  - lgkm-only barriers in the K-loop (x loads stay in flight).
//  - B fragments global->VGPR per phase from the L2-hot 256 KB blob.
// ---------------------------------------------------------------------------

typedef __attribute__((ext_vector_type(8))) short bf16x8;
typedef __attribute__((ext_vector_type(4))) short s16x4;
typedef __attribute__((ext_vector_type(4))) float f32x4;

__device__ __forceinline__ short f2bf(float f) {
  unsigned u = __float_as_uint(f);
  unsigned r = (u + 0x7FFFu + ((u >> 16) & 1u)) >> 16;   // RNE
  return (short)r;
}

// 4 fp32 -> 4 bf16 via 2x v_cvt_pk_bf16_f32 (RNE in HW)
__device__ __forceinline__ s16x4 pack4(f32x4 v) {
  union { unsigned u[2]; s16x4 s; } cv;
  asm("v_cvt_pk_bf16_f32 %0, %2, %3\n\t"
      "v_cvt_pk_bf16_f32 %1, %4, %5"
      : "=&v"(cv.u[0]), "=&v"(cv.u[1])
      : "v"(v[0]), "v"(v[1]), "v"(v[2]), "v"(v[3]));
  return cv.s;
}

// ---------------------------------------------------------------------------
// prep_w: fp32 W[k][n] (256x256) -> bf16 blob in MFMA B-fragment order:
//   blob[mat][ks][ct*64+lane][j] = W[ks*32 + (lane>>4)*8 + j][ct*16 + (lane&15)]
// mat 0 = W_gate, mat 1 = W_lin. One block per (mat, ks) slice.
// Also zeroes the sums buffer.
// ---------------------------------------------------------------------------
__global__ __launch_bounds__(256) void prep_w(const float* __restrict__ Wg,
                                              const float* __restrict__ Wl,
                                              short* __restrict__ blob,
                                              float* __restrict__ sums) {
  __shared__ __align__(16) float tile[32][260];
  const int b = blockIdx.x;
  const int mat = b >> 3, ks = b & 7;
  const float* W = mat ? Wl : Wg;
  const int tid = threadIdx.x;
  {
    f32x4 z = (f32x4)(0.0f);
    #pragma unroll
    for (int i = 0; i < 8; ++i)
      *(f32x4*)&sums[(size_t)(i * 4096 + b * 256 + tid) * 4] = z;
  }
  #pragma unroll
  for (int i = 0; i < 8; ++i) {
    int f4 = tid + i * 256;
    int kl = f4 >> 6;
    int c0 = (f4 & 63) * 4;
    f32x4 v = *(const f32x4*)&W[(ks * 32 + kl) * 256 + c0];
    tile[kl][c0 + 0] = v[0]; tile[kl][c0 + 1] = v[1];
    tile[kl][c0 + 2] = v[2]; tile[kl][c0 + 3] = v[3];
  }
  __syncthreads();
  #pragma unroll
  for (int i = 0; i < 4; ++i) {
    int chunk = tid + i * 256;           // ct*64 + lane
    int ln = chunk & 63;
    int n  = ((chunk >> 6) << 4) + (ln & 15);
    int k0 = (ln >> 4) * 8;
    bf16x8 o;
    #pragma unroll
    for (int j = 0; j < 8; ++j) o[j] = f2bf(tile[k0 + j][n]);
    *(bf16x8*)&blob[(size_t)(mat * 8 + ks) * 8192 + (size_t)chunk * 8] = o;
  }
}

// ---------------------------------------------------------------------------
// fused_main: persistent. 64 rows/tile, 512 threads (8 waves), wave =
// col-group (32 cols x 2 mats). Per wave per phase: 4 A x 4 B frags, 16 MFMA.
// Slab (bf16, 2048 shorts = 4 KB): chunk c = r*64+lane holds
//   x[row0 + r*16 + (lane&15)][ks*32 + (lane>>4)*8 .. +7].
// Staging: thread tid packs 4 floats -> 4 bf16 at short-offset tid*4
// (byte tid*8: lane-linear, conflict-free). Source offset carries the
// fragment swizzle. A-frag read: ds_read_b128 at chunk (r*64+lane).
// ---------------------------------------------------------------------------
__global__ __launch_bounds__(512, 4) void
fused_main(const float* __restrict__ x,
           const int* __restrict__ batch,
           const float* __restrict__ b_lin,
           const float* __restrict__ b_gate,
           const short* __restrict__ blob,
           float* __restrict__ sums,
           int ntiles) {
  __shared__ __align__(16) short xs[2 * 2048];    // 2 bf16 slabs, 8 KB
  __shared__ __align__(16) float pmax[64 * 8];    // [row][wave] 2 KB
  __shared__ __align__(16) float psum[64 * 8];    // 2 KB
  __shared__ int batch_l[64];

  const int tid  = threadIdx.x;
  const int lane = tid & 63;
  const int wave = tid >> 6;            // col-group 0..7 (32 cols each)
  const int quad = lane >> 4;
  const int ln15 = lane & 15;

  // contiguous tile range for this block
  const int nb = gridDim.x;
  const int tq = ntiles / nb, tr = ntiles % nb;
  const int t_first = blockIdx.x * tq + (blockIdx.x < tr ? blockIdx.x : tr);
  const int t_count = tq + (blockIdx.x < tr ? 1 : 0);

  // staging thread mapping (granule = tid, 16B fp32 source -> 8B bf16 dest)
  const int s_r = tid >> 7;             // row-tile 0..3
  const int s_l = (tid >> 1) & 63;      // chunk lane
  const int s_h = tid & 1;              // k-half (4 floats)
  const size_t s_goff = (size_t)(s_r * 16 + (s_l & 15)) * 256
                      + (s_l >> 4) * 8 + s_h * 4;
  const int s_loff = tid * 4;           // shorts

  const short* bptr = blob + (size_t)(wave * 128 + lane) * 8;

  // biases: block-invariant, hoisted
  const float bg0 = b_gate[wave * 32 + ln15];
  const float bg1 = b_gate[wave * 32 + 16 + ln15];
  const float bl0 = b_lin [wave * 32 + ln15];
  const float bl1 = b_lin [wave * 32 + 16 + ln15];

  long long row0 = (long long)t_first * 64;
  const float* tptr = x + (size_t)row0 * 256 + s_goff;

  // ---- block prologue (once): slab0, pend(ks1), batch tile ----
  {
    f32x4 c0 = __builtin_nontemporal_load((const f32x4*)tptr);
    *(s16x4*)&xs[s_loff] = pack4(c0);
  }
  f32x4 pend = __builtin_nontemporal_load((const f32x4*)(tptr + 32));
  if (tid < 64) batch_l[tid] = batch[row0 + tid];
  asm volatile("s_waitcnt lgkmcnt(0)\ns_barrier" ::: "memory");

  for (int ti = 0; ti < t_count; ++ti) {
    const float* nptr = (ti + 1 < t_count) ? tptr + 64 * 256 : tptr;

    f32x4 accz[4][2], accs[4][2];
    #pragma unroll
    for (int r = 0; r < 4; ++r)
      #pragma unroll
      for (int c = 0; c < 2; ++c) {
        accz[r][c] = (f32x4)(0.0f);
        accs[r][c] = (f32x4)(0.0f);
      }

    #pragma unroll
    for (int ks = 0; ks < 8; ++ks) {
      // load data for global phase +2 (wraps into next tile at ks>=6)
      const float* nsrc = (ks < 6) ? (tptr + (ks + 2) * 32)
                                   : (nptr + (ks - 6) * 32);
      f32x4 nxt = __builtin_nontemporal_load((const f32x4*)nsrc);
      // B fragments for this ks (L2-hot blob)
      bf16x8 bz0 = *(const bf16x8*)(bptr + (size_t)ks * 8192);
      bf16x8 bz1 = *(const bf16x8*)(bptr + (size_t)ks * 8192 + 512);
      bf16x8 bs0 = *(const bf16x8*)(bptr + (size_t)(8 + ks) * 8192);
      bf16x8 bs1 = *(const bf16x8*)(bptr + (size_t)(8 + ks) * 8192 + 512);
      const short* xb = xs + (ks & 1) * 2048;
      #pragma unroll
      for (int r = 0; r < 4; ++r) {
        bf16x8 a = *(const bf16x8*)(xb + (r * 64 + lane) * 8);
        accz[r][0] = __builtin_amdgcn_mfma_f32_16x16x32_bf16(a, bz0, accz[r][0], 0, 0, 0);
        accz[r][1] = __builtin_amdgcn_mfma_f32_16x16x32_bf16(a, bz1, accz[r][1], 0, 0, 0);
        accs[r][0] = __builtin_amdgcn_mfma_f32_16x16x32_bf16(a, bs0, accs[r][0], 0, 0, 0);
        accs[r][1] = __builtin_amdgcn_mfma_f32_16x16x32_bf16(a, bs1, accs[r][1], 0, 0, 0);
      }
      // stage phase ks+1 (at ks=7: next tile's ks0 into slab0)
      *(s16x4*)&xs[((ks + 1) & 1) * 2048 + s_loff] = pack4(pend);
      asm volatile("s_waitcnt lgkmcnt(0)\ns_barrier" ::: "memory");
      pend = nxt;
    }

    // ---- biases ----
    #pragma unroll
    for (int r = 0; r < 4; ++r)
      #pragma unroll
      for (int e = 0; e < 4; ++e) {
        accz[r][0][e] += bg0;
        accz[r][1][e] += bg1;
      }

    // ---- softmax over 256 cols per row (split across the 8 waves) ----
    #pragma unroll
    for (int r = 0; r < 4; ++r)
      #pragma unroll
      for (int e = 0; e < 4; ++e) {
        float v = fmaxf(accz[r][0][e], accz[r][1][e]);
        v = fmaxf(v, __shfl_xor(v, 1));
        v = fmaxf(v, __shfl_xor(v, 2));
        v = fmaxf(v, __shfl_xor(v, 4));
        v = fmaxf(v, __shfl_xor(v, 8));
        if (ln15 == 0) pmax[(r * 16 + quad * 4 + e) * 8 + wave] = v;
      }
    __syncthreads();
    #pragma unroll
    for (int r = 0; r < 4; ++r)
      #pragma unroll
      for (int e = 0; e < 4; ++e) {
        const int rl = r * 16 + quad * 4 + e;
        f32x4 m0 = *(const f32x4*)&pmax[rl * 8];
        f32x4 m1 = *(const f32x4*)&pmax[rl * 8 + 4];
        float fm = fmaxf(fmaxf(fmaxf(m0[0], m0[1]), fmaxf(m0[2], m0[3])),
                         fmaxf(fmaxf(m1[0], m1[1]), fmaxf(m1[2], m1[3])));
        float e0 = __expf(accz[r][0][e] - fm);
        float e1 = __expf(accz[r][1][e] - fm);
        accz[r][0][e] = e0;
        accz[r][1][e] = e1;
        float s = e0 + e1;
        s += __shfl_xor(s, 1);
        s += __shfl_xor(s, 2);
        s += __shfl_xor(s, 4);
        s += __shfl_xor(s, 8);
        if (ln15 == 0) psum[rl * 8 + wave] = s;
      }
    __syncthreads();
    #pragma unroll
    for (int r = 0; r < 4; ++r)
      #pragma unroll
      for (int e = 0; e < 4; ++e) {
        const int rl = r * 16 + quad * 4 + e;
        f32x4 s0 = *(const f32x4*)&psum[rl * 8];
        f32x4 s1 = *(const f32x4*)&psum[rl * 8 + 4];
        float inv = 1.0f / (s0[0] + s0[1] + s0[2] + s0[3] +
                            s1[0] + s1[1] + s1[2] + s1[3]);
        accs[r][0][e] = (accs[r][0][e] + bl0) * (accz[r][0][e] * inv);  // gated
        accs[r][1][e] = (accs[r][1][e] + bl1) * (accz[r][1][e] * inv);
      }

    // ---- segment pooling: masked reduce, quad shuffles, direct atomics ----
    const int b0 = batch_l[0], b1 = batch_l[63];
    for (int g = b0; g <= b1; ++g) {
      float cs0 = 0.0f, cs1 = 0.0f;
      #pragma unroll
      for (int r = 0; r < 4; ++r)
        #pragma unroll
        for (int e = 0; e < 4; ++e) {
          const int rl = r * 16 + quad * 4 + e;
          const float msk = (batch_l[rl] == g) ? 1.0f : 0.0f;
          cs0 = fmaf(accs[r][0][e], msk, cs0);
          cs1 = fmaf(accs[r][1][e], msk, cs1);
        }
      cs0 += __shfl_xor(cs0, 16); cs0 += __shfl_xor(cs0, 32);
      cs1 += __shfl_xor(cs1, 16); cs1 += __shfl_xor(cs1, 32);
      if (quad == 0) {
        atomicAdd(&sums[(size_t)g * 256 + wave * 32 + ln15], cs0);
        atomicAdd(&sums[(size_t)g * 256 + wave * 32 + 16 + ln15], cs1);
      }
    }

    // ---- advance to next tile: reload batch tile behind a guard barrier ----
    if (ti + 1 < t_count) {
      __syncthreads();                          // protect batch_l overwrite
      if (tid < 64) batch_l[tid] = batch[row0 + (long long)(ti + 1) * 64 + tid];
      tptr = nptr;
    }
  }
}

// ---------------------------------------------------------------------------
// finalize (in-place: io holds per-graph sums on entry, final output on exit)
// ---------------------------------------------------------------------------
__device__ __forceinline__ int lbound(const int* a, int n, int v) {
  int lo = 0, hi = n;
  while (lo < hi) {
    int mid = (lo + hi) >> 1;
    if (a[mid] < v) lo = mid + 1; else hi = mid;
  }
  return lo;
}

__global__ __launch_bounds__(256) void finalize(float* io,
                                                const int* __restrict__ batch, int N,
                                                const float* __restrict__ W_fin,
                                                const float* __restrict__ b_fin) {
  __shared__ __align__(16) float mrow[256];
  __shared__ float s_inv;
  const int g = blockIdx.x, tid = threadIdx.x;
  if (tid == 0) {
    int cnt = lbound(batch, N, g + 1) - lbound(batch, N, g);
    s_inv = 1.0f / fmaxf((float)cnt, 1.0f);
  }
  __syncthreads();
  mrow[tid] = io[(size_t)g * 256 + tid] * s_inv;
  __syncthreads();
  float acc = b_fin[tid];
  #pragma unroll 8
  for (int k = 0; k < 256; ++k)
    acc = fmaf(mrow[k], W_fin[k * 256 + tid], acc);
  io[(size_t)g * 256 + tid] = acc;
}

// ---------------------------------------------------------------------------
extern "C" void kernel_launch(void* const* d_in, const int* in_sizes, int n_in,
                              void* d_out, int out_size, void* d_ws, size_t ws_size,
                              hipStream_t stream) {
  const float* x      = (const float*)d_in[0];
  // d_in[1] = edge_index: unused by the reference
  const int*   batch  = (const int*)d_in[2];     // harness passes integers as int32
  const float* W_lin  = (const float*)d_in[3];
  const float* b_lin  = (const float*)d_in[4];
  const float* W_gate = (const float*)d_in[5];
  const float* b_gate = (const float*)d_in[6];
  const float* W_fin  = (const float*)d_in[7];
  const float* b_fin  = (const float*)d_in[8];
  float* out = (float*)d_out;                    // doubles as the sums buffer
  const int N = in_sizes[2];                     // 400000

  short* blob = (short*)d_ws;                    // 256 KB bf16 weight blob

  prep_w<<<16, 256, 0, stream>>>(W_gate, W_lin, blob, out);
  fused_main<<<512, 512, 0, stream>>>(x, batch, b_lin, b_gate,
                                      (const short*)blob, out, N / 64);
  finalize<<<512, 256, 0, stream>>>(out, batch, N, W_fin, b_fin);
}